// Round 1
// baseline (479.245 us; speedup 1.0000x reference)
//
#include <hip/hip_runtime.h>
#include <hip/hip_bf16.h>

#define N_NODES 50000
#define N_EDGES 600000
#define HID 128
#define LN_EPS 1e-5f

// ---------------------------------------------------------------- CSR build
__global__ __launch_bounds__(256) void count_kernel(const int* __restrict__ ei,
                                                    int* __restrict__ deg, int E) {
    int i = blockIdx.x * blockDim.x + threadIdx.x;
    if (i < E) atomicAdd(&deg[ei[E + i]], 1);
}

__global__ __launch_bounds__(1024) void scan_kernel(const int* __restrict__ deg,
                                                    int* __restrict__ row_ptr,
                                                    int* __restrict__ cursor,
                                                    float* __restrict__ inv_cnt, int n) {
    __shared__ int buf[1024];
    __shared__ int carry;
    int t = threadIdx.x;
    if (t == 0) carry = 0;
    for (int base = 0; base < n; base += 1024) {
        int i = base + t;
        int v = (i < n) ? deg[i] : 0;
        __syncthreads();              // protects carry write + buf reuse from prev chunk
        buf[t] = v;
        __syncthreads();
        for (int off = 1; off < 1024; off <<= 1) {
            int x = (t >= off) ? buf[t - off] : 0;
            __syncthreads();
            buf[t] += x;
            __syncthreads();
        }
        int incl = buf[t];
        int excl = incl - v;
        int c = carry;
        __syncthreads();              // all threads read carry before update
        if (t == 1023) carry = c + incl;
        if (i < n) {
            row_ptr[i] = c + excl;
            cursor[i]  = c + excl;
            inv_cnt[i] = 1.0f / (float)(v + 1);   // +1 self loop
        }
    }
    __syncthreads();
    if (t == 0) row_ptr[n] = carry;
}

__global__ __launch_bounds__(256) void fill_kernel(const int* __restrict__ ei,
                                                   int* __restrict__ cursor,
                                                   int* __restrict__ col, int E) {
    int i = blockIdx.x * blockDim.x + threadIdx.x;
    if (i < E) {
        int s = ei[i];
        int d = ei[E + i];
        int p = atomicAdd(&cursor[d], 1);
        col[p] = s;
    }
}

// ---------------------------------------------------------------- GEMM  out = A@W + b
// A:[N,K] f32, W:[K,128], b:[128]. W+b staged in LDS. 256 thr, 32 rows/block,
// each thread: 4 rows x 4 cols register tile (16 FMA per ds_read_b128).
template <int K>
__global__ __launch_bounds__(256) void gemm_kernel(const float* __restrict__ A,
                                                   const float* __restrict__ W,
                                                   const float* __restrict__ b,
                                                   float* __restrict__ out, int N) {
    __shared__ float Wl[K * 128];
    __shared__ float bl[128];
    int t = threadIdx.x;
    for (int i = t; i < K * 32; i += 256)
        ((float4*)Wl)[i] = ((const float4*)W)[i];
    if (t < 128) bl[t] = b[t];
    __syncthreads();

    int cg = t & 31;              // columns 4*cg .. 4*cg+3
    int rs = t >> 5;              // 0..7
    int r0 = blockIdx.x * 32 + rs * 4;

    const float4* Wl4 = (const float4*)Wl;
    float4 bias = ((const float4*)bl)[cg];
    float4 acc0 = bias, acc1 = bias, acc2 = bias, acc3 = bias;

    int ra = min(r0 + 0, N - 1);
    int rb = min(r0 + 1, N - 1);
    int rc = min(r0 + 2, N - 1);
    int rd = min(r0 + 3, N - 1);

    for (int k = 0; k < K; k += 4) {
        float4 w0 = Wl4[(k + 0) * 32 + cg];
        float4 w1 = Wl4[(k + 1) * 32 + cg];
        float4 w2 = Wl4[(k + 2) * 32 + cg];
        float4 w3 = Wl4[(k + 3) * 32 + cg];
        float4 a0 = *(const float4*)&A[(size_t)ra * K + k];
        float4 a1 = *(const float4*)&A[(size_t)rb * K + k];
        float4 a2 = *(const float4*)&A[(size_t)rc * K + k];
        float4 a3 = *(const float4*)&A[(size_t)rd * K + k];
#define FMA4(ACC, AV)                                                          \
        ACC.x += AV.x * w0.x; ACC.y += AV.x * w0.y; ACC.z += AV.x * w0.z; ACC.w += AV.x * w0.w; \
        ACC.x += AV.y * w1.x; ACC.y += AV.y * w1.y; ACC.z += AV.y * w1.z; ACC.w += AV.y * w1.w; \
        ACC.x += AV.z * w2.x; ACC.y += AV.z * w2.y; ACC.z += AV.z * w2.z; ACC.w += AV.z * w2.w; \
        ACC.x += AV.w * w3.x; ACC.y += AV.w * w3.y; ACC.z += AV.w * w3.z; ACC.w += AV.w * w3.w;
        FMA4(acc0, a0)
        FMA4(acc1, a1)
        FMA4(acc2, a2)
        FMA4(acc3, a3)
#undef FMA4
    }
    if (r0 + 0 < N) ((float4*)&out[(size_t)(r0 + 0) * 128])[cg] = acc0;
    if (r0 + 1 < N) ((float4*)&out[(size_t)(r0 + 1) * 128])[cg] = acc1;
    if (r0 + 2 < N) ((float4*)&out[(size_t)(r0 + 2) * 128])[cg] = acc2;
    if (r0 + 3 < N) ((float4*)&out[(size_t)(r0 + 3) * 128])[cg] = acc3;
}

// ------------------------------------------------- aggregate + mean + ReLU + LN
// one wave (64 lanes) per node; 2 floats per lane.
__global__ __launch_bounds__(256) void agg_norm_kernel(
    const float* __restrict__ h,       // [N,128] post-linear
    const int* __restrict__ row_ptr,
    const int* __restrict__ col,
    const float* __restrict__ inv_cnt,
    const float* __restrict__ g, const float* __restrict__ be,
    float* __restrict__ out, int N) {
    int wave = (int)((blockIdx.x * (size_t)blockDim.x + threadIdx.x) >> 6);
    int lane = threadIdx.x & 63;
    if (wave >= N) return;
    int n = wave;
    const float2* h2 = (const float2*)h;
    float2 acc = h2[(size_t)n * 64 + lane];          // self loop
    int beg = row_ptr[n], end = row_ptr[n + 1];
    for (int e = beg; e < end; ++e) {
        int j = col[e];                               // uniform across wave
        float2 v = h2[(size_t)j * 64 + lane];
        acc.x += v.x; acc.y += v.y;
    }
    float ic = inv_cnt[n];
    float s0 = fmaxf(acc.x * ic, 0.0f);
    float s1 = fmaxf(acc.y * ic, 0.0f);
    float sum = s0 + s1;
    float sq  = s0 * s0 + s1 * s1;
    for (int off = 1; off < 64; off <<= 1) {
        sum += __shfl_xor(sum, off);
        sq  += __shfl_xor(sq, off);
    }
    float mu  = sum * (1.0f / 128.0f);
    float var = sq * (1.0f / 128.0f) - mu * mu;
    float rs  = rsqrtf(var + LN_EPS);
    float2 gg = ((const float2*)g)[lane];
    float2 bb = ((const float2*)be)[lane];
    float2 o;
    o.x = gg.x * (s0 - mu) * rs + bb.x;
    o.y = gg.y * (s1 - mu) * rs + bb.y;
    ((float2*)out)[(size_t)n * 64 + lane] = o;
}

// ---------------------------------------------------------------- launch
extern "C" void kernel_launch(void* const* d_in, const int* in_sizes, int n_in,
                              void* d_out, int out_size, void* d_ws, size_t ws_size,
                              hipStream_t stream) {
    const float* x  = (const float*)d_in[0];
    const int*   ei = (const int*)d_in[1];
    const float* W1 = (const float*)d_in[2];
    const float* b1 = (const float*)d_in[3];
    const float* W2 = (const float*)d_in[4];
    const float* b2 = (const float*)d_in[5];
    const float* W3 = (const float*)d_in[6];
    const float* b3 = (const float*)d_in[7];
    const float* g1 = (const float*)d_in[8];
    const float* be1 = (const float*)d_in[9];
    const float* g2 = (const float*)d_in[10];
    const float* be2 = (const float*)d_in[11];
    const float* g3 = (const float*)d_in[12];
    const float* be3 = (const float*)d_in[13];
    float* out = (float*)d_out;

    const int N = N_NODES, E = N_EDGES;
    char* w = (char*)d_ws;
    float* hL     = (float*)w;  w += (size_t)N * 128 * sizeof(float);   // 25.6 MB
    int*   col    = (int*)w;    w += (size_t)E * sizeof(int);           // 2.4 MB
    int*   rowp   = (int*)w;    w += (size_t)(N + 1) * sizeof(int);
    int*   cursor = (int*)w;    w += (size_t)N * sizeof(int);
    int*   deg    = (int*)w;    w += (size_t)N * sizeof(int);
    float* invc   = (float*)w;  w += (size_t)N * sizeof(float);

    hipMemsetAsync(deg, 0, (size_t)N * sizeof(int), stream);
    count_kernel<<<(E + 255) / 256, 256, 0, stream>>>(ei, deg, E);
    scan_kernel<<<1, 1024, 0, stream>>>(deg, rowp, cursor, invc, N);
    fill_kernel<<<(E + 255) / 256, 256, 0, stream>>>(ei, cursor, col, E);

    const int gemm_blocks = (N + 31) / 32;
    const int agg_blocks  = (N + 3) / 4;   // 4 waves per 256-thread block

    // layer 1
    gemm_kernel<64><<<gemm_blocks, 256, 0, stream>>>(x, W1, b1, hL, N);
    agg_norm_kernel<<<agg_blocks, 256, 0, stream>>>(hL, rowp, col, invc, g1, be1, out, N);
    // layer 2
    gemm_kernel<128><<<gemm_blocks, 256, 0, stream>>>(out, W2, b2, hL, N);
    agg_norm_kernel<<<agg_blocks, 256, 0, stream>>>(hL, rowp, col, invc, g2, be2, out, N);
    // layer 3
    gemm_kernel<128><<<gemm_blocks, 256, 0, stream>>>(out, W3, b3, hL, N);
    agg_norm_kernel<<<agg_blocks, 256, 0, stream>>>(hL, rowp, col, invc, g3, be3, out, N);
}

// Round 2
// 445.701 us; speedup vs baseline: 1.0753x; 1.0753x over previous
//
#include <hip/hip_runtime.h>
#include <hip/hip_bf16.h>

#define N_NODES 50000
#define N_EDGES 600000
#define HID 128
#define LN_EPS 1e-5f

// ---------------------------------------------------------------- CSR build
__global__ __launch_bounds__(256) void count_kernel(const int* __restrict__ ei,
                                                    int* __restrict__ deg, int E) {
    int i = blockIdx.x * blockDim.x + threadIdx.x;
    if (i < E) atomicAdd(&deg[ei[E + i]], 1);
}

// Single-block register-blocked exclusive scan over N_NODES degrees.
// 1024 threads x ITEMS=49 elements each, 2 barriers total.
__global__ __launch_bounds__(1024) void scan_kernel(const int* __restrict__ deg,
                                                    int* __restrict__ row_ptr,
                                                    int* __restrict__ cursor,
                                                    float* __restrict__ inv_cnt, int n) {
    constexpr int ITEMS = (N_NODES + 1023) / 1024;   // 49
    int t = threadIdx.x;
    int lane = t & 63, wid = t >> 6;
    int base = t * ITEMS;

    int v[ITEMS];
    int local = 0;
#pragma unroll
    for (int i = 0; i < ITEMS; ++i) {
        int idx = base + i;
        v[i] = (idx < n) ? deg[idx] : 0;
        local += v[i];
    }
    // wave-inclusive scan of per-thread totals
    int incl = local;
#pragma unroll
    for (int off = 1; off < 64; off <<= 1) {
        int x = __shfl_up(incl, off);
        if (lane >= off) incl += x;
    }
    __shared__ int wsum[16];
    if (lane == 63) wsum[wid] = incl;
    __syncthreads();
    int woff = 0;
    for (int i = 0; i < wid; ++i) woff += wsum[i];

    int run = woff + (incl - local);   // exclusive offset of this thread's segment
#pragma unroll
    for (int i = 0; i < ITEMS; ++i) {
        int idx = base + i;
        if (idx < n) {
            row_ptr[idx] = run;
            cursor[idx]  = run;
            inv_cnt[idx] = 1.0f / (float)(v[i] + 1);   // +1 self loop
        }
        run += v[i];
    }
    if (t == 1023) row_ptr[n] = run;   // total (tail v[] are 0 past n)
}

__global__ __launch_bounds__(256) void fill_kernel(const int* __restrict__ ei,
                                                   int* __restrict__ cursor,
                                                   int* __restrict__ col, int E) {
    int i = blockIdx.x * blockDim.x + threadIdx.x;
    if (i < E) {
        int s = ei[i];
        int d = ei[E + i];
        int p = atomicAdd(&cursor[d], 1);
        col[p] = s;
    }
}

// ---------------------------------------------------------------- GEMM  out = A@W + b
template <int K>
__global__ __launch_bounds__(256) void gemm_kernel(const float* __restrict__ A,
                                                   const float* __restrict__ W,
                                                   const float* __restrict__ b,
                                                   float* __restrict__ out, int N) {
    __shared__ float Wl[K * 128];
    __shared__ float bl[128];
    int t = threadIdx.x;
    for (int i = t; i < K * 32; i += 256)
        ((float4*)Wl)[i] = ((const float4*)W)[i];
    if (t < 128) bl[t] = b[t];
    __syncthreads();

    int cg = t & 31;              // columns 4*cg .. 4*cg+3
    int rs = t >> 5;              // 0..7
    int r0 = blockIdx.x * 32 + rs * 4;

    const float4* Wl4 = (const float4*)Wl;
    float4 bias = ((const float4*)bl)[cg];
    float4 acc0 = bias, acc1 = bias, acc2 = bias, acc3 = bias;

    int ra = min(r0 + 0, N - 1);
    int rb = min(r0 + 1, N - 1);
    int rc = min(r0 + 2, N - 1);
    int rd = min(r0 + 3, N - 1);

    for (int k = 0; k < K; k += 4) {
        float4 w0 = Wl4[(k + 0) * 32 + cg];
        float4 w1 = Wl4[(k + 1) * 32 + cg];
        float4 w2 = Wl4[(k + 2) * 32 + cg];
        float4 w3 = Wl4[(k + 3) * 32 + cg];
        float4 a0 = *(const float4*)&A[(size_t)ra * K + k];
        float4 a1 = *(const float4*)&A[(size_t)rb * K + k];
        float4 a2 = *(const float4*)&A[(size_t)rc * K + k];
        float4 a3 = *(const float4*)&A[(size_t)rd * K + k];
#define FMA4(ACC, AV)                                                          \
        ACC.x += AV.x * w0.x; ACC.y += AV.x * w0.y; ACC.z += AV.x * w0.z; ACC.w += AV.x * w0.w; \
        ACC.x += AV.y * w1.x; ACC.y += AV.y * w1.y; ACC.z += AV.y * w1.z; ACC.w += AV.y * w1.w; \
        ACC.x += AV.z * w2.x; ACC.y += AV.z * w2.y; ACC.z += AV.z * w2.z; ACC.w += AV.z * w2.w; \
        ACC.x += AV.w * w3.x; ACC.y += AV.w * w3.y; ACC.z += AV.w * w3.z; ACC.w += AV.w * w3.w;
        FMA4(acc0, a0)
        FMA4(acc1, a1)
        FMA4(acc2, a2)
        FMA4(acc3, a3)
#undef FMA4
    }
    if (r0 + 0 < N) ((float4*)&out[(size_t)(r0 + 0) * 128])[cg] = acc0;
    if (r0 + 1 < N) ((float4*)&out[(size_t)(r0 + 1) * 128])[cg] = acc1;
    if (r0 + 2 < N) ((float4*)&out[(size_t)(r0 + 2) * 128])[cg] = acc2;
    if (r0 + 3 < N) ((float4*)&out[(size_t)(r0 + 3) * 128])[cg] = acc3;
}

// ------------------------------------------------- aggregate + mean + ReLU + LN
// one wave (64 lanes) per node; 2 floats per lane. col indices preloaded
// (one coalesced load per wave) and broadcast via shfl to avoid a dependent
// uniform load per edge.
__global__ __launch_bounds__(256) void agg_norm_kernel(
    const float* __restrict__ h,       // [N,128] post-linear
    const int* __restrict__ row_ptr,
    const int* __restrict__ col,
    const float* __restrict__ inv_cnt,
    const float* __restrict__ g, const float* __restrict__ be,
    float* __restrict__ out, int N) {
    int wave = (int)((blockIdx.x * (size_t)blockDim.x + threadIdx.x) >> 6);
    int lane = threadIdx.x & 63;
    if (wave >= N) return;
    int n = wave;
    const float2* h2 = (const float2*)h;
    float2 acc = h2[(size_t)n * 64 + lane];          // self loop
    int beg = row_ptr[n], end = row_ptr[n + 1];
    int cnt = end - beg;
    int myc = (lane < cnt) ? col[beg + lane] : 0;    // covers deg <= 64 (typ. ~12)
    for (int e = 0; e < cnt; ++e) {
        int j = (e < 64) ? __shfl(myc, e) : col[beg + e];
        float2 v = h2[(size_t)j * 64 + lane];
        acc.x += v.x; acc.y += v.y;
    }
    float ic = inv_cnt[n];
    float s0 = fmaxf(acc.x * ic, 0.0f);
    float s1 = fmaxf(acc.y * ic, 0.0f);
    float sum = s0 + s1;
    float sq  = s0 * s0 + s1 * s1;
    for (int off = 1; off < 64; off <<= 1) {
        sum += __shfl_xor(sum, off);
        sq  += __shfl_xor(sq, off);
    }
    float mu  = sum * (1.0f / 128.0f);
    float var = sq * (1.0f / 128.0f) - mu * mu;
    float rs  = rsqrtf(var + LN_EPS);
    float2 gg = ((const float2*)g)[lane];
    float2 bb = ((const float2*)be)[lane];
    float2 o;
    o.x = gg.x * (s0 - mu) * rs + bb.x;
    o.y = gg.y * (s1 - mu) * rs + bb.y;
    ((float2*)out)[(size_t)n * 64 + lane] = o;
}

// ---------------------------------------------------------------- launch
extern "C" void kernel_launch(void* const* d_in, const int* in_sizes, int n_in,
                              void* d_out, int out_size, void* d_ws, size_t ws_size,
                              hipStream_t stream) {
    const float* x  = (const float*)d_in[0];
    const int*   ei = (const int*)d_in[1];
    const float* W1 = (const float*)d_in[2];
    const float* b1 = (const float*)d_in[3];
    const float* W2 = (const float*)d_in[4];
    const float* b2 = (const float*)d_in[5];
    const float* W3 = (const float*)d_in[6];
    const float* b3 = (const float*)d_in[7];
    const float* g1 = (const float*)d_in[8];
    const float* be1 = (const float*)d_in[9];
    const float* g2 = (const float*)d_in[10];
    const float* be2 = (const float*)d_in[11];
    const float* g3 = (const float*)d_in[12];
    const float* be3 = (const float*)d_in[13];
    float* out = (float*)d_out;

    const int N = N_NODES, E = N_EDGES;
    char* w = (char*)d_ws;
    float* hL     = (float*)w;  w += (size_t)N * 128 * sizeof(float);   // 25.6 MB
    int*   col    = (int*)w;    w += (size_t)E * sizeof(int);           // 2.4 MB
    int*   rowp   = (int*)w;    w += (size_t)(N + 1) * sizeof(int);
    int*   cursor = (int*)w;    w += (size_t)N * sizeof(int);
    int*   deg    = (int*)w;    w += (size_t)N * sizeof(int);
    float* invc   = (float*)w;  w += (size_t)N * sizeof(float);

    hipMemsetAsync(deg, 0, (size_t)N * sizeof(int), stream);
    count_kernel<<<(E + 255) / 256, 256, 0, stream>>>(ei, deg, E);
    scan_kernel<<<1, 1024, 0, stream>>>(deg, rowp, cursor, invc, N);
    fill_kernel<<<(E + 255) / 256, 256, 0, stream>>>(ei, cursor, col, E);

    const int gemm_blocks = (N + 31) / 32;
    const int agg_blocks  = (N + 3) / 4;   // 4 waves per 256-thread block

    // layer 1
    gemm_kernel<64><<<gemm_blocks, 256, 0, stream>>>(x, W1, b1, hL, N);
    agg_norm_kernel<<<agg_blocks, 256, 0, stream>>>(hL, rowp, col, invc, g1, be1, out, N);
    // layer 2
    gemm_kernel<128><<<gemm_blocks, 256, 0, stream>>>(out, W2, b2, hL, N);
    agg_norm_kernel<<<agg_blocks, 256, 0, stream>>>(hL, rowp, col, invc, g2, be2, out, N);
    // layer 3
    gemm_kernel<128><<<gemm_blocks, 256, 0, stream>>>(out, W3, b3, hL, N);
    agg_norm_kernel<<<agg_blocks, 256, 0, stream>>>(hL, rowp, col, invc, g3, be3, out, N);
}

// Round 3
// 351.228 us; speedup vs baseline: 1.3645x; 1.2690x over previous
//
#include <hip/hip_runtime.h>
#include <hip/hip_bf16.h>

#define N_NODES 50000
#define N_EDGES 600000
#define HID 128
#define LN_EPS 1e-5f

#define SCAN_BLOCK 1024
#define SCAN_NBLK ((N_NODES + SCAN_BLOCK - 1) / SCAN_BLOCK)   // 49

// ---------------------------------------------------------------- CSR build
__global__ __launch_bounds__(256) void count_kernel(const int* __restrict__ ei,
                                                    int* __restrict__ deg, int E) {
    int i = blockIdx.x * blockDim.x + threadIdx.x;
    if (i < E) atomicAdd(&deg[ei[E + i]], 1);
}

// Phase A: per-block sums (coalesced).
__global__ __launch_bounds__(SCAN_BLOCK) void deg_partial_kernel(const int* __restrict__ deg,
                                                                 int* __restrict__ partials, int n) {
    int t = threadIdx.x;
    int i = blockIdx.x * SCAN_BLOCK + t;
    int v = (i < n) ? deg[i] : 0;
    int s = v;
#pragma unroll
    for (int off = 1; off < 64; off <<= 1) s += __shfl_xor(s, off);
    __shared__ int ws[SCAN_BLOCK / 64];
    if ((t & 63) == 0) ws[t >> 6] = s;
    __syncthreads();
    if (t == 0) {
        int tot = 0;
#pragma unroll
        for (int w = 0; w < SCAN_BLOCK / 64; ++w) tot += ws[w];
        partials[blockIdx.x] = tot;
    }
}

// Phase B: one wave scans the 49 block partials (exclusive), writes total.
__global__ __launch_bounds__(64) void scan_partials_kernel(int* __restrict__ partials,
                                                           int* __restrict__ row_ptr, int nblk) {
    int lane = threadIdx.x;
    int v = (lane < nblk) ? partials[lane] : 0;
    int incl = v;
#pragma unroll
    for (int off = 1; off < 64; off <<= 1) {
        int x = __shfl_up(incl, off);
        if (lane >= off) incl += x;
    }
    if (lane < nblk) partials[lane] = incl - v;     // exclusive block offset
    if (lane == 63) row_ptr[N_NODES] = incl;        // grand total
}

// Phase C: block-wide exclusive scan + block offset (coalesced).
__global__ __launch_bounds__(SCAN_BLOCK) void scan_final_kernel(const int* __restrict__ deg,
                                                                const int* __restrict__ partials,
                                                                int* __restrict__ row_ptr,
                                                                int* __restrict__ cursor,
                                                                float* __restrict__ inv_cnt, int n) {
    int t = threadIdx.x;
    int i = blockIdx.x * SCAN_BLOCK + t;
    int v = (i < n) ? deg[i] : 0;
    int lane = t & 63, wid = t >> 6;
    int incl = v;
#pragma unroll
    for (int off = 1; off < 64; off <<= 1) {
        int x = __shfl_up(incl, off);
        if (lane >= off) incl += x;
    }
    __shared__ int ws[SCAN_BLOCK / 64];
    if (lane == 63) ws[wid] = incl;
    __syncthreads();
    int woff = 0;
    for (int w = 0; w < wid; ++w) woff += ws[w];
    int excl = partials[blockIdx.x] + woff + (incl - v);
    if (i < n) {
        row_ptr[i] = excl;
        cursor[i]  = excl;
        inv_cnt[i] = 1.0f / (float)(v + 1);          // +1 self loop
    }
}

__global__ __launch_bounds__(256) void fill_kernel(const int* __restrict__ ei,
                                                   int* __restrict__ cursor,
                                                   int* __restrict__ col, int E) {
    int i = blockIdx.x * blockDim.x + threadIdx.x;
    if (i < E) {
        int s = ei[i];
        int d = ei[E + i];
        int p = atomicAdd(&cursor[d], 1);
        col[p] = s;
    }
}

// ---------------------------------------------------------------- GEMM  out = A@W + b
template <int K>
__global__ __launch_bounds__(256) void gemm_kernel(const float* __restrict__ A,
                                                   const float* __restrict__ W,
                                                   const float* __restrict__ b,
                                                   float* __restrict__ out, int N) {
    __shared__ float Wl[K * 128];
    __shared__ float bl[128];
    int t = threadIdx.x;
    for (int i = t; i < K * 32; i += 256)
        ((float4*)Wl)[i] = ((const float4*)W)[i];
    if (t < 128) bl[t] = b[t];
    __syncthreads();

    int cg = t & 31;              // columns 4*cg .. 4*cg+3
    int rs = t >> 5;              // 0..7
    int r0 = blockIdx.x * 32 + rs * 4;

    const float4* Wl4 = (const float4*)Wl;
    float4 bias = ((const float4*)bl)[cg];
    float4 acc0 = bias, acc1 = bias, acc2 = bias, acc3 = bias;

    int ra = min(r0 + 0, N - 1);
    int rb = min(r0 + 1, N - 1);
    int rc = min(r0 + 2, N - 1);
    int rd = min(r0 + 3, N - 1);

    for (int k = 0; k < K; k += 4) {
        float4 w0 = Wl4[(k + 0) * 32 + cg];
        float4 w1 = Wl4[(k + 1) * 32 + cg];
        float4 w2 = Wl4[(k + 2) * 32 + cg];
        float4 w3 = Wl4[(k + 3) * 32 + cg];
        float4 a0 = *(const float4*)&A[(size_t)ra * K + k];
        float4 a1 = *(const float4*)&A[(size_t)rb * K + k];
        float4 a2 = *(const float4*)&A[(size_t)rc * K + k];
        float4 a3 = *(const float4*)&A[(size_t)rd * K + k];
#define FMA4(ACC, AV)                                                          \
        ACC.x += AV.x * w0.x; ACC.y += AV.x * w0.y; ACC.z += AV.x * w0.z; ACC.w += AV.x * w0.w; \
        ACC.x += AV.y * w1.x; ACC.y += AV.y * w1.y; ACC.z += AV.y * w1.z; ACC.w += AV.y * w1.w; \
        ACC.x += AV.z * w2.x; ACC.y += AV.z * w2.y; ACC.z += AV.z * w2.z; ACC.w += AV.z * w2.w; \
        ACC.x += AV.w * w3.x; ACC.y += AV.w * w3.y; ACC.z += AV.w * w3.z; ACC.w += AV.w * w3.w;
        FMA4(acc0, a0)
        FMA4(acc1, a1)
        FMA4(acc2, a2)
        FMA4(acc3, a3)
#undef FMA4
    }
    if (r0 + 0 < N) ((float4*)&out[(size_t)(r0 + 0) * 128])[cg] = acc0;
    if (r0 + 1 < N) ((float4*)&out[(size_t)(r0 + 1) * 128])[cg] = acc1;
    if (r0 + 2 < N) ((float4*)&out[(size_t)(r0 + 2) * 128])[cg] = acc2;
    if (r0 + 3 < N) ((float4*)&out[(size_t)(r0 + 3) * 128])[cg] = acc3;
}

// ------------------------------------------------- aggregate + mean + ReLU + LN
__global__ __launch_bounds__(256) void agg_norm_kernel(
    const float* __restrict__ h,       // [N,128] post-linear
    const int* __restrict__ row_ptr,
    const int* __restrict__ col,
    const float* __restrict__ inv_cnt,
    const float* __restrict__ g, const float* __restrict__ be,
    float* __restrict__ out, int N) {
    int wave = (int)((blockIdx.x * (size_t)blockDim.x + threadIdx.x) >> 6);
    int lane = threadIdx.x & 63;
    if (wave >= N) return;
    int n = wave;
    const float2* h2 = (const float2*)h;
    float2 acc = h2[(size_t)n * 64 + lane];          // self loop
    int beg = row_ptr[n], end = row_ptr[n + 1];
    int cnt = end - beg;
    int myc = (lane < cnt) ? col[beg + lane] : 0;    // covers deg <= 64 (typ. ~12)
    for (int e = 0; e < cnt; ++e) {
        int j = (e < 64) ? __shfl(myc, e) : col[beg + e];
        float2 v = h2[(size_t)j * 64 + lane];
        acc.x += v.x; acc.y += v.y;
    }
    float ic = inv_cnt[n];
    float s0 = fmaxf(acc.x * ic, 0.0f);
    float s1 = fmaxf(acc.y * ic, 0.0f);
    float sum = s0 + s1;
    float sq  = s0 * s0 + s1 * s1;
#pragma unroll
    for (int off = 1; off < 64; off <<= 1) {
        sum += __shfl_xor(sum, off);
        sq  += __shfl_xor(sq, off);
    }
    float mu  = sum * (1.0f / 128.0f);
    float var = sq * (1.0f / 128.0f) - mu * mu;
    float rs  = rsqrtf(var + LN_EPS);
    float2 gg = ((const float2*)g)[lane];
    float2 bb = ((const float2*)be)[lane];
    float2 o;
    o.x = gg.x * (s0 - mu) * rs + bb.x;
    o.y = gg.y * (s1 - mu) * rs + bb.y;
    ((float2*)out)[(size_t)n * 64 + lane] = o;
}

// ---------------------------------------------------------------- launch
extern "C" void kernel_launch(void* const* d_in, const int* in_sizes, int n_in,
                              void* d_out, int out_size, void* d_ws, size_t ws_size,
                              hipStream_t stream) {
    const float* x  = (const float*)d_in[0];
    const int*   ei = (const int*)d_in[1];
    const float* W1 = (const float*)d_in[2];
    const float* b1 = (const float*)d_in[3];
    const float* W2 = (const float*)d_in[4];
    const float* b2 = (const float*)d_in[5];
    const float* W3 = (const float*)d_in[6];
    const float* b3 = (const float*)d_in[7];
    const float* g1 = (const float*)d_in[8];
    const float* be1 = (const float*)d_in[9];
    const float* g2 = (const float*)d_in[10];
    const float* be2 = (const float*)d_in[11];
    const float* g3 = (const float*)d_in[12];
    const float* be3 = (const float*)d_in[13];
    float* out = (float*)d_out;

    const int N = N_NODES, E = N_EDGES;
    char* w = (char*)d_ws;
    float* hL     = (float*)w;  w += (size_t)N * 128 * sizeof(float);   // 25.6 MB
    int*   col    = (int*)w;    w += (size_t)E * sizeof(int);           // 2.4 MB
    int*   rowp   = (int*)w;    w += (size_t)(N + 1) * sizeof(int);
    int*   cursor = (int*)w;    w += (size_t)N * sizeof(int);
    int*   deg    = (int*)w;    w += (size_t)N * sizeof(int);
    float* invc   = (float*)w;  w += (size_t)N * sizeof(float);
    int*   parts  = (int*)w;    w += (size_t)SCAN_NBLK * sizeof(int);

    hipMemsetAsync(deg, 0, (size_t)N * sizeof(int), stream);
    count_kernel<<<(E + 255) / 256, 256, 0, stream>>>(ei, deg, E);
    deg_partial_kernel<<<SCAN_NBLK, SCAN_BLOCK, 0, stream>>>(deg, parts, N);
    scan_partials_kernel<<<1, 64, 0, stream>>>(parts, rowp, SCAN_NBLK);
    scan_final_kernel<<<SCAN_NBLK, SCAN_BLOCK, 0, stream>>>(deg, parts, rowp, cursor, invc, N);
    fill_kernel<<<(E + 255) / 256, 256, 0, stream>>>(ei, cursor, col, E);

    const int gemm_blocks = (N + 31) / 32;
    const int agg_blocks  = (N + 3) / 4;   // 4 waves per 256-thread block

    // layer 1
    gemm_kernel<64><<<gemm_blocks, 256, 0, stream>>>(x, W1, b1, hL, N);
    agg_norm_kernel<<<agg_blocks, 256, 0, stream>>>(hL, rowp, col, invc, g1, be1, out, N);
    // layer 2
    gemm_kernel<128><<<gemm_blocks, 256, 0, stream>>>(out, W2, b2, hL, N);
    agg_norm_kernel<<<agg_blocks, 256, 0, stream>>>(hL, rowp, col, invc, g2, be2, out, N);
    // layer 3
    gemm_kernel<128><<<gemm_blocks, 256, 0, stream>>>(out, W3, b3, hL, N);
    agg_norm_kernel<<<agg_blocks, 256, 0, stream>>>(hL, rowp, col, invc, g3, be3, out, N);
}